// Round 3
// baseline (165.489 us; speedup 1.0000x reference)
//
#include <hip/hip_runtime.h>

// YOLO loss on MI355X — round 3: single fused kernel.
// pred/target: (B, 14, 14, 30) f32. One 256-thread block stages a 256-cell
// tile (30720 B per tensor) into LDS via aligned float4 loads, each thread
// computes one cell's loss, block reduces, then device-scope atomicAdd into
// an accumulator in d_ws. Last block (ticket counter) writes total/B to d_out.
// d_ws[0..1]: {float accumulator, uint ticket} — zeroed via hipMemsetAsync.

#define TILE 256

__global__ __launch_bounds__(256) void yolo_fused_kernel(
    const float* __restrict__ pred, const float* __restrict__ targ,
    float* __restrict__ acc, unsigned* __restrict__ ticket,
    float* __restrict__ out, int n_cells, float inv_batch)
{
    __shared__ float4 lds_p4[TILE * 30 / 4];   // 30 KB
    __shared__ float4 lds_t4[TILE * 30 / 4];   // 30 KB
    float* lds_p = reinterpret_cast<float*>(lds_p4);
    float* lds_t = reinterpret_cast<float*>(lds_t4);

    const int t = threadIdx.x;
    const int cell0 = blockIdx.x * TILE;
    const int tile_cells = min(TILE, n_cells - cell0);

    if (tile_cells == TILE) {
        // fast path: full tile, base 16B-aligned (256*30*4 = 30720 B)
        const float4* gp = reinterpret_cast<const float4*>(pred + (size_t)cell0 * 30);
        const float4* gt = reinterpret_cast<const float4*>(targ + (size_t)cell0 * 30);
#pragma unroll
        for (int i = 0; i < 7; ++i) {
            lds_p4[i * 256 + t] = gp[i * 256 + t];
            lds_t4[i * 256 + t] = gt[i * 256 + t];
        }
        if (t < 128) {
            lds_p4[7 * 256 + t] = gp[7 * 256 + t];
            lds_t4[7 * 256 + t] = gt[7 * 256 + t];
        }
    } else {
        int nf = tile_cells * 30;
        const float* gp = pred + (size_t)cell0 * 30;
        const float* gt = targ + (size_t)cell0 * 30;
        for (int i = t; i < nf; i += 256) {
            lds_p[i] = gp[i];
            lds_t[i] = gt[i];
        }
    }
    __syncthreads();

    float loss = 0.0f;
    if (t < tile_cells) {
        const float* pv = lds_p + t * 30;   // stride-30 -> 4-way LDS aliasing,
        const float* tv = lds_t + t * 30;   // 1.58x on a tiny traffic: negligible

        float conf_t = tv[4];
        if (conf_t == 0.0f) {
            float d4 = pv[4] - tv[4];
            float d9 = pv[9] - tv[9];
            loss = 0.5f * (d4 * d4 + d9 * d9);
        } else {
            float cls = 0.0f;
#pragma unroll
            for (int c = 10; c < 30; ++c) {
                float d = pv[c] - tv[c];
                cls += d * d;
            }

            // target box 0 -> xyxy (mirror reference arithmetic exactly)
            float t0x = tv[0] / 14.0f, t0y = tv[1] / 14.0f;
            float tx1 = t0x - 0.5f * tv[2], ty1 = t0y - 0.5f * tv[3];
            float tx2 = t0x + 0.5f * tv[2], ty2 = t0y + 0.5f * tv[3];
            float area_t = (tx2 - tx1) * (ty2 - ty1);

            float iou0, iou1;
#pragma unroll
            for (int b = 0; b < 2; ++b) {
                float bx = pv[5*b + 0] / 14.0f, by = pv[5*b + 1] / 14.0f;
                float px1 = bx - 0.5f * pv[5*b + 2], py1 = by - 0.5f * pv[5*b + 3];
                float px2 = bx + 0.5f * pv[5*b + 2], py2 = by + 0.5f * pv[5*b + 3];
                float ltx = fmaxf(px1, tx1), lty = fmaxf(py1, ty1);
                float rbx = fminf(px2, tx2), rby = fminf(py2, ty2);
                float iw = fmaxf(rbx - ltx, 0.0f), ih = fmaxf(rby - lty, 0.0f);
                float inter = iw * ih;
                float area_p = (px2 - px1) * (py2 - py1);
                float v = inter / (area_p + area_t - inter);
                if (b == 0) iou0 = v; else iou1 = v;
            }

            bool sel1 = iou1 > iou0;          // tie -> box 0 (argmax semantics)
            float max_iou = sel1 ? iou1 : iou0;

            float ps0 = sel1 ? pv[5] : pv[0];
            float ps1 = sel1 ? pv[6] : pv[1];
            float ps2 = sel1 ? pv[7] : pv[2];
            float ps3 = sel1 ? pv[8] : pv[3];
            float ps4 = sel1 ? pv[9] : pv[4];
            float ts0 = sel1 ? tv[5] : tv[0];
            float ts1 = sel1 ? tv[6] : tv[1];
            float ts2 = sel1 ? tv[7] : tv[2];
            float ts3 = sel1 ? tv[8] : tv[3];
            float notresp_conf = sel1 ? pv[4] : pv[9];

            float dconf = ps4 - max_iou;
            float dx = ps0 - ts0, dy = ps1 - ts1;
            float dw = sqrtf(ps2) - sqrtf(ts2);
            float dh = sqrtf(ps3) - sqrtf(ts3);
            float loc = dx * dx + dy * dy + dw * dw + dh * dh;

            loss = 5.0f * loc + 2.0f * dconf * dconf
                 + notresp_conf * notresp_conf + cls;
        }
    }

    // wave (64-lane) shuffle reduction
#pragma unroll
    for (int off = 32; off > 0; off >>= 1)
        loss += __shfl_down(loss, off, 64);

    __shared__ float wsum[4];
    int lane = threadIdx.x & 63;
    int wid  = threadIdx.x >> 6;
    if (lane == 0) wsum[wid] = loss;
    __syncthreads();

    if (threadIdx.x == 0) {
        float bsum = (wsum[0] + wsum[1]) + (wsum[2] + wsum[3]);
        atomicAdd(acc, bsum);                 // device-scope (global atomics)
        __threadfence();                      // publish before ticket
        unsigned my = atomicAdd(ticket, 1u);
        if (my == gridDim.x - 1) {
            __threadfence();                  // acquire
            float total = atomicAdd(acc, 0.0f); // device-scope read, no stale L1
            out[0] = total * inv_batch;
        }
    }
}

extern "C" void kernel_launch(void* const* d_in, const int* in_sizes, int n_in,
                              void* d_out, int out_size, void* d_ws, size_t ws_size,
                              hipStream_t stream) {
    const float* pred = (const float*)d_in[0];
    const float* targ = (const float*)d_in[1];
    float* out = (float*)d_out;
    float* acc = (float*)d_ws;
    unsigned* ticket = (unsigned*)d_ws + 1;

    int n_elems  = in_sizes[0];         // B*14*14*30
    int n_cells  = n_elems / 30;        // B*196
    int n_batch  = n_cells / (14 * 14); // B
    int n_blocks = (n_cells + TILE - 1) / TILE;

    // zero accumulator + ticket (graph-capturable async memset node)
    hipMemsetAsync(d_ws, 0, 2 * sizeof(float), stream);

    yolo_fused_kernel<<<n_blocks, 256, 0, stream>>>(
        pred, targ, acc, ticket, out, n_cells, 1.0f / (float)n_batch);
}

// Round 4
// 113.776 us; speedup vs baseline: 1.4545x; 1.4545x over previous
//
#include <hip/hip_runtime.h>

// YOLO loss on MI355X — round 4: high-occupancy small tiles.
// pred/target: (B, 14, 14, 30) f32. One 64-thread (1-wave) block stages a
// 64-cell tile (7680 B per tensor, fused 15360 B LDS image) with aligned
// float4 loads, computes one cell per thread, wave-reduces, writes one
// partial per block. 15 KB LDS -> 10 blocks/CU (vs 2 at 60 KB in round 2);
// single-wave workgroup => barrier elided, stage/compute of different
// blocks overlap freely. Deterministic two-kernel reduction (round-3's
// atomic+threadfence tail regressed 2.5x -- reverted).

#define TILE 64

__global__ __launch_bounds__(64) void yolo_cell_kernel(
    const float* __restrict__ pred, const float* __restrict__ targ,
    float* __restrict__ block_sums, int n_cells)
{
    __shared__ float4 lds4[TILE * 30 * 2 / 4];  // 960 float4 = 15360 B
    float* lds = reinterpret_cast<float*>(lds4);
    const float* lds_p = lds;                   // floats [0, 1920)
    const float* lds_t = lds + TILE * 30;       // floats [1920, 3840)

    const int t = threadIdx.x;                  // 0..63, one wave
    const int cell0 = blockIdx.x * TILE;
    const int tile_cells = min(TILE, n_cells - cell0);

    if (tile_cells == TILE) {
        // full tile: bases 16B-aligned (64*30*4 = 7680 B per tile)
        const float4* gp = reinterpret_cast<const float4*>(pred + (size_t)cell0 * 30);
        const float4* gt = reinterpret_cast<const float4*>(targ + (size_t)cell0 * 30);
#pragma unroll
        for (int i = 0; i < 15; ++i) {
            int k = i * 64 + t;                 // 0..959
            // k < 480 -> pred float4 k ; else targ float4 k-480.
            // Only i==7 splits the wave (lanes <32 pred / >=32 targ).
            lds4[k] = (k < 480) ? gp[k] : gt[k - 480];
        }
    } else {
        // generic tail (not taken when n_cells % 64 == 0)
        int nf = tile_cells * 30;
        const float* gp = pred + (size_t)cell0 * 30;
        const float* gt = targ + (size_t)cell0 * 30;
        for (int i = t; i < nf; i += 64) {
            lds[i] = gp[i];
            lds[TILE * 30 + i] = gt[i];
        }
    }
    __syncthreads();   // single-wave workgroup: elided by compiler

    float loss = 0.0f;
    if (t < tile_cells) {
        const float* pv = lds_p + t * 30;   // stride-30 -> 4-way LDS aliasing,
        const float* tv = lds_t + t * 30;   // tiny traffic: negligible

        float conf_t = tv[4];
        if (conf_t == 0.0f) {
            float d4 = pv[4] - tv[4];
            float d9 = pv[9] - tv[9];
            loss = 0.5f * (d4 * d4 + d9 * d9);
        } else {
            float cls = 0.0f;
#pragma unroll
            for (int c = 10; c < 30; ++c) {
                float d = pv[c] - tv[c];
                cls += d * d;
            }

            // target box 0 -> xyxy (mirror reference arithmetic exactly)
            float t0x = tv[0] / 14.0f, t0y = tv[1] / 14.0f;
            float tx1 = t0x - 0.5f * tv[2], ty1 = t0y - 0.5f * tv[3];
            float tx2 = t0x + 0.5f * tv[2], ty2 = t0y + 0.5f * tv[3];
            float area_t = (tx2 - tx1) * (ty2 - ty1);

            float iou0, iou1;
#pragma unroll
            for (int b = 0; b < 2; ++b) {
                float bx = pv[5*b + 0] / 14.0f, by = pv[5*b + 1] / 14.0f;
                float px1 = bx - 0.5f * pv[5*b + 2], py1 = by - 0.5f * pv[5*b + 3];
                float px2 = bx + 0.5f * pv[5*b + 2], py2 = by + 0.5f * pv[5*b + 3];
                float ltx = fmaxf(px1, tx1), lty = fmaxf(py1, ty1);
                float rbx = fminf(px2, tx2), rby = fminf(py2, ty2);
                float iw = fmaxf(rbx - ltx, 0.0f), ih = fmaxf(rby - lty, 0.0f);
                float inter = iw * ih;
                float area_p = (px2 - px1) * (py2 - py1);
                float v = inter / (area_p + area_t - inter);
                if (b == 0) iou0 = v; else iou1 = v;
            }

            bool sel1 = iou1 > iou0;          // tie -> box 0 (argmax semantics)
            float max_iou = sel1 ? iou1 : iou0;

            float ps0 = sel1 ? pv[5] : pv[0];
            float ps1 = sel1 ? pv[6] : pv[1];
            float ps2 = sel1 ? pv[7] : pv[2];
            float ps3 = sel1 ? pv[8] : pv[3];
            float ps4 = sel1 ? pv[9] : pv[4];
            float ts0 = sel1 ? tv[5] : tv[0];
            float ts1 = sel1 ? tv[6] : tv[1];
            float ts2 = sel1 ? tv[7] : tv[2];
            float ts3 = sel1 ? tv[8] : tv[3];
            float notresp_conf = sel1 ? pv[4] : pv[9];

            float dconf = ps4 - max_iou;
            float dx = ps0 - ts0, dy = ps1 - ts1;
            float dw = sqrtf(ps2) - sqrtf(ts2);
            float dh = sqrtf(ps3) - sqrtf(ts3);
            float loc = dx * dx + dy * dy + dw * dw + dh * dh;

            loss = 5.0f * loc + 2.0f * dconf * dconf
                 + notresp_conf * notresp_conf + cls;
        }
    }

    // wave (64-lane) shuffle reduction; lane 0 writes the block partial
#pragma unroll
    for (int off = 32; off > 0; off >>= 1)
        loss += __shfl_down(loss, off, 64);
    if (t == 0)
        block_sums[blockIdx.x] = loss;
}

__global__ __launch_bounds__(1024) void yolo_reduce_kernel(
    const float* __restrict__ block_sums, int n, double inv_batch,
    float* __restrict__ out)
{
    double acc = 0.0;
    for (int i = threadIdx.x; i < n; i += 1024)
        acc += (double)block_sums[i];
#pragma unroll
    for (int off = 32; off > 0; off >>= 1)
        acc += __shfl_down(acc, off, 64);

    __shared__ double wsum[16];
    int lane = threadIdx.x & 63;
    int wid  = threadIdx.x >> 6;
    if (lane == 0) wsum[wid] = acc;
    __syncthreads();
    if (threadIdx.x == 0) {
        double s = 0.0;
#pragma unroll
        for (int w = 0; w < 16; ++w) s += wsum[w];
        out[0] = (float)(s * inv_batch);
    }
}

extern "C" void kernel_launch(void* const* d_in, const int* in_sizes, int n_in,
                              void* d_out, int out_size, void* d_ws, size_t ws_size,
                              hipStream_t stream) {
    const float* pred = (const float*)d_in[0];
    const float* targ = (const float*)d_in[1];
    float* out = (float*)d_out;
    float* block_sums = (float*)d_ws;  // fully written before read; poison ok

    int n_elems  = in_sizes[0];         // B*14*14*30
    int n_cells  = n_elems / 30;        // B*196
    int n_batch  = n_cells / (14 * 14); // B
    int n_blocks = (n_cells + TILE - 1) / TILE;   // 6272 for B=2048

    yolo_cell_kernel<<<n_blocks, TILE, 0, stream>>>(pred, targ, block_sums, n_cells);
    yolo_reduce_kernel<<<1, 1024, 0, stream>>>(block_sums, n_blocks,
                                               1.0 / (double)n_batch, out);
}